// Round 7
// baseline (1934.415 us; speedup 1.0000x reference)
//
#include <hip/hip_runtime.h>

#define NGRAPH 100
#define NPER   1000
#define NNODES 100000
#define NEDGES 1600000
#define EPG    16000   // edges per graph

// ==================== small utility kernels ====================
__global__ __launch_bounds__(256) void zero_int_k(int* __restrict__ p, int n) {
    int i = blockIdx.x * 256 + threadIdx.x;
    if (i < n) p[i] = 0;
}
__global__ __launch_bounds__(256) void zero_float_k(float* __restrict__ p, int n) {
    int i = blockIdx.x * 256 + threadIdx.x;
    if (i < n) p[i] = 0.f;
}

// ==================== counting sort of edges by DST ====================
__global__ __launch_bounds__(256) void hist_k(const int* __restrict__ dst,
                                              int* __restrict__ count) {
    int e = blockIdx.x * 256 + threadIdx.x;
    if (e < NEDGES) atomicAdd(&count[dst[e]], 1);
}

__global__ __launch_bounds__(1024) void scan_k(const int* __restrict__ count,
                                               int* __restrict__ offs,
                                               int* __restrict__ cursor) {
    __shared__ int sc[1024];
    int t = threadIdx.x, g = blockIdx.x;
    int v = (t < NPER) ? count[g * NPER + t] : 0;
    sc[t] = v;
    __syncthreads();
    for (int s = 1; s < 1024; s <<= 1) {
        int add = (t >= s) ? sc[t - s] : 0;
        __syncthreads();
        sc[t] += add;
        __syncthreads();
    }
    if (t < NPER) {
        int start = g * EPG + sc[t] - v;   // exclusive
        offs[g * NPER + t]   = start;
        cursor[g * NPER + t] = start;
    }
}

// stores pre-scaled indices: {src*32, etype*32, elabel*32, etype*4}
__global__ __launch_bounds__(256) void scatter_k(
    const int* __restrict__ src, const int* __restrict__ dst,
    const int* __restrict__ et, const int* __restrict__ el,
    int* __restrict__ cursor, int4* __restrict__ sorted) {
    int e = blockIdx.x * 256 + threadIdx.x;
    if (e >= NEDGES) return;
    int d = dst[e];
    int p = atomicAdd(&cursor[d], 1);
    int et_ = et[e];
    sorted[p] = make_int4(src[e] * 32, et_ * 32, el[e] * 32, et_ * 4);
}

// ==================== fused node projections, 2 nodes/thread (LEAN) ========
// Register discipline: only one weight-group's accumulators live at a time.
// basis section: pA[4]+pB[4] (32 VGPR) -> b-minor float4 transpose-pack.
// A1 / A2 / selfw sections: 2 float4 each, stored immediately.
__global__ __launch_bounds__(256) void node2_k(
    const float* __restrict__ h, const float* __restrict__ basis_l,
    const float* __restrict__ selfw_l, const float* __restrict__ Aw_l,
    float* __restrict__ xproj, float* __restrict__ psrc,
    float* __restrict__ pdst, float* __restrict__ selfp)
{
    __shared__ float w_s[7168]; // [0,4096) basis, [4096,5120) selfw, [5120,7168) A1|A2
    {
        const float4* b4 = (const float4*)basis_l;  // 1024
        const float4* s4 = (const float4*)selfw_l;  // 256
        const float4* a4 = (const float4*)Aw_l;     // 512 (rows 0..63)
        float4* w4 = (float4*)w_s;
        for (int k = threadIdx.x; k < 1792; k += 256) {
            float4 v;
            if (k < 1024)      v = b4[k];
            else if (k < 1280) v = s4[k - 1024];
            else               v = a4[k - 1280];
            w4[k] = v;
        }
    }
    __syncthreads();

    const int nA = blockIdx.x * 512 + threadIdx.x;
    const int nB = nA + 256;
    const bool vA = (nA < NNODES);
    const bool vB = (nB < NNODES);
    const int lA = vA ? nA : 0;
    const int lB = vB ? nB : 0;

    float hA[32], hB[32];
    {
        const float4* hpA = (const float4*)(h + (size_t)lA * 32);
        const float4* hpB = (const float4*)(h + (size_t)lB * 32);
        #pragma unroll
        for (int k = 0; k < 8; k++) {
            float4 a = hpA[k], b = hpB[k];
            hA[4*k+0]=a.x; hA[4*k+1]=a.y; hA[4*k+2]=a.z; hA[4*k+3]=a.w;
            hB[4*k+0]=b.x; hB[4*k+1]=b.y; hB[4*k+2]=b.z; hB[4*k+3]=b.w;
        }
    }

    float* xoutA = xproj + (size_t)lA * 128;
    float* xoutB = xproj + (size_t)lB * 128;

    #pragma unroll 1
    for (int oc = 0; oc < 8; oc++) {
        // ---- basis: 4 matrices -> transpose-packed b-minor xproj ----
        {
            float4 pA[4], pB[4];
            #pragma unroll
            for (int b = 0; b < 4; b++) {
                const float* wb = w_s + b * 1024 + oc * 4;
                float4 a = {0.f,0.f,0.f,0.f}, c = {0.f,0.f,0.f,0.f};
                #pragma unroll
                for (int d = 0; d < 32; d++) {
                    float4 wv = *(const float4*)(wb + d * 32);
                    a.x = fmaf(hA[d], wv.x, a.x);  c.x = fmaf(hB[d], wv.x, c.x);
                    a.y = fmaf(hA[d], wv.y, a.y);  c.y = fmaf(hB[d], wv.y, c.y);
                    a.z = fmaf(hA[d], wv.z, a.z);  c.z = fmaf(hB[d], wv.z, c.z);
                    a.w = fmaf(hA[d], wv.w, a.w);  c.w = fmaf(hB[d], wv.w, c.w);
                }
                pA[b] = a; pB[b] = c;
            }
            if (vA) {
                *(float4*)(xoutA + (oc*4+0)*4) = make_float4(pA[0].x,pA[1].x,pA[2].x,pA[3].x);
                *(float4*)(xoutA + (oc*4+1)*4) = make_float4(pA[0].y,pA[1].y,pA[2].y,pA[3].y);
                *(float4*)(xoutA + (oc*4+2)*4) = make_float4(pA[0].z,pA[1].z,pA[2].z,pA[3].z);
                *(float4*)(xoutA + (oc*4+3)*4) = make_float4(pA[0].w,pA[1].w,pA[2].w,pA[3].w);
            }
            if (vB) {
                *(float4*)(xoutB + (oc*4+0)*4) = make_float4(pB[0].x,pB[1].x,pB[2].x,pB[3].x);
                *(float4*)(xoutB + (oc*4+1)*4) = make_float4(pB[0].y,pB[1].y,pB[2].y,pB[3].y);
                *(float4*)(xoutB + (oc*4+2)*4) = make_float4(pB[0].z,pB[1].z,pB[2].z,pB[3].z);
                *(float4*)(xoutB + (oc*4+3)*4) = make_float4(pB[0].w,pB[1].w,pB[2].w,pB[3].w);
            }
        }
        // ---- A1 -> psrc ----
        {
            const float* wb = w_s + 5120 + oc * 4;
            float4 a = {0.f,0.f,0.f,0.f}, c = {0.f,0.f,0.f,0.f};
            #pragma unroll
            for (int d = 0; d < 32; d++) {
                float4 wv = *(const float4*)(wb + d * 32);
                a.x = fmaf(hA[d], wv.x, a.x);  c.x = fmaf(hB[d], wv.x, c.x);
                a.y = fmaf(hA[d], wv.y, a.y);  c.y = fmaf(hB[d], wv.y, c.y);
                a.z = fmaf(hA[d], wv.z, a.z);  c.z = fmaf(hB[d], wv.z, c.z);
                a.w = fmaf(hA[d], wv.w, a.w);  c.w = fmaf(hB[d], wv.w, c.w);
            }
            if (vA) *(float4*)(psrc + (size_t)lA*32 + oc*4) = a;
            if (vB) *(float4*)(psrc + (size_t)lB*32 + oc*4) = c;
        }
        // ---- A2 -> pdst ----
        {
            const float* wb = w_s + 6144 + oc * 4;
            float4 a = {0.f,0.f,0.f,0.f}, c = {0.f,0.f,0.f,0.f};
            #pragma unroll
            for (int d = 0; d < 32; d++) {
                float4 wv = *(const float4*)(wb + d * 32);
                a.x = fmaf(hA[d], wv.x, a.x);  c.x = fmaf(hB[d], wv.x, c.x);
                a.y = fmaf(hA[d], wv.y, a.y);  c.y = fmaf(hB[d], wv.y, c.y);
                a.z = fmaf(hA[d], wv.z, a.z);  c.z = fmaf(hB[d], wv.z, c.z);
                a.w = fmaf(hA[d], wv.w, a.w);  c.w = fmaf(hB[d], wv.w, c.w);
            }
            if (vA) *(float4*)(pdst + (size_t)lA*32 + oc*4) = a;
            if (vB) *(float4*)(pdst + (size_t)lB*32 + oc*4) = c;
        }
        // ---- selfw -> selfp ----
        {
            const float* wb = w_s + 4096 + oc * 4;
            float4 a = {0.f,0.f,0.f,0.f}, c = {0.f,0.f,0.f,0.f};
            #pragma unroll
            for (int d = 0; d < 32; d++) {
                float4 wv = *(const float4*)(wb + d * 32);
                a.x = fmaf(hA[d], wv.x, a.x);  c.x = fmaf(hB[d], wv.x, c.x);
                a.y = fmaf(hA[d], wv.y, a.y);  c.y = fmaf(hB[d], wv.y, c.y);
                a.z = fmaf(hA[d], wv.z, a.z);  c.z = fmaf(hB[d], wv.z, c.z);
                a.w = fmaf(hA[d], wv.w, a.w);  c.w = fmaf(hB[d], wv.w, c.w);
            }
            if (vA) *(float4*)(selfp + (size_t)lA*32 + oc*4) = a;
            if (vB) *(float4*)(selfp + (size_t)lB*32 + oc*4) = c;
        }
    }
}

// ==================== per-relation attention tables ====================
__global__ __launch_bounds__(64) void rel_tables_k(
    const float* __restrict__ attn_tab, const float* __restrict__ Aw_l,
    const float* __restrict__ Ab_l, float* __restrict__ t1, float* __restrict__ t2)
{
    int r = blockIdx.x;
    int t = threadIdx.x;
    int o = t & 31;
    bool second = t >= 32;
    const float* at = attn_tab + r * 32;
    const float* W  = Aw_l + (second ? 96*32 : 64*32);
    float acc = second ? 0.f : Ab_l[o];
    #pragma unroll
    for (int d = 0; d < 32; d++) acc += at[d] * W[d*32 + o];
    (second ? t2 : t1)[r*32 + o] = acc;
}

// ==================== CSR edge kernel: 1 wave/node, 4 edges/iter ===========
__global__ __launch_bounds__(256) void edge_csr_k(
    const int4* __restrict__ sorted, const int* __restrict__ offs,
    const float* __restrict__ psrc, const float* __restrict__ pdst,
    const float* __restrict__ t1,   const float* __restrict__ t2,
    const float* __restrict__ xproj, const float* __restrict__ selfp,
    const float* __restrict__ wcomp_l,
    const float* __restrict__ Bw, const float* __restrict__ Bb,
    float* __restrict__ h_next)
{
    // XCD-bijective swizzle: 25000 blocks, 25000 % 8 == 0.
    const int CPX = 25000 / 8;
    int bid = (int)blockIdx.x;
    bid = (bid % 8) * CPX + bid / 8;

    const int wib  = threadIdx.x >> 6;   // wave in block: 0..3
    const int lane = threadIdx.x & 63;
    const int p    = lane >> 5;          // edge of pair
    const int i    = lane & 31;          // channel
    const int n    = bid * 4 + wib;      // dst node

    const int start = offs[n];
    const int end   = (n == NNODES - 1) ? NEDGES : offs[n + 1];
    const float bw = Bw[i];
    const float bb = Bb[0];
    const float pd = pdst[(size_t)n * 32 + i];

    float acc0 = 0.f, acc1 = 0.f;
    for (int e0 = start; e0 < end; e0 += 4) {
        int ea = e0 + p;
        int eb = e0 + 2 + p;
        bool va = (ea < end);
        bool vb = (eb < end);
        int4 eda = sorted[va ? ea : e0];      // {s*32, et*32, el*32, et*4}
        int4 edb = sorted[vb ? eb : e0];
        int ta = eda.x + i;
        int tb = edb.x + i;
        float psa = psrc[ta];
        float psb = psrc[tb];
        float4 xva = *(const float4*)(xproj + (size_t)ta * 4);
        float4 xvb = *(const float4*)(xproj + (size_t)tb * 4);
        float t1a = t1[eda.y + i], t1b = t1[edb.y + i];
        float t2a = t2[eda.z + i], t2b = t2[edb.z + i];
        float4 ca = *(const float4*)(wcomp_l + eda.w);
        float4 cb = *(const float4*)(wcomp_l + edb.w);

        float za = fmaxf(psa + pd + t1a + t2a, 0.f);
        float zb = fmaxf(psb + pd + t1b + t2b, 0.f);
        float pa = za * bw, pb = zb * bw;
        pa += __shfl_xor(pa, 1, 32);   pb += __shfl_xor(pb, 1, 32);
        pa += __shfl_xor(pa, 2, 32);   pb += __shfl_xor(pb, 2, 32);
        pa += __shfl_xor(pa, 4, 32);   pb += __shfl_xor(pb, 4, 32);
        pa += __shfl_xor(pa, 8, 32);   pb += __shfl_xor(pb, 8, 32);
        pa += __shfl_xor(pa, 16, 32);  pb += __shfl_xor(pb, 16, 32);
        float aa = __builtin_amdgcn_rcpf(1.f + __expf(-(pa + bb)));
        float ab = __builtin_amdgcn_rcpf(1.f + __expf(-(pb + bb)));
        aa = va ? aa : 0.f;
        ab = vb ? ab : 0.f;
        float msga = ca.x*xva.x + ca.y*xva.y + ca.z*xva.z + ca.w*xva.w;
        float msgb = cb.x*xvb.x + cb.y*xvb.y + cb.z*xvb.z + cb.w*xvb.w;
        acc0 = fmaf(aa, msga, acc0);
        acc1 = fmaf(ab, msgb, acc1);
    }
    float acc = acc0 + acc1;
    acc += __shfl_xor(acc, 32, 64);      // combine the two edge-halves
    if (p == 0) {
        float hv = fmaxf(acc + selfp[(size_t)n*32 + i], 0.f);
        h_next[(size_t)n*32 + i] = hv;
    }
}

// ==================== per-graph mean (8 slices) + head/tail (y=8) ==========
__global__ __launch_bounds__(256) void mean_ht_k(
    const float* __restrict__ h, const int* __restrict__ head_ids,
    const int* __restrict__ tail_ids, float* __restrict__ g_acc,
    float* __restrict__ head_buf, float* __restrict__ tail_buf, int l)
{
    int g  = blockIdx.x;
    int sl = blockIdx.y;
    int i  = threadIdx.x & 31;
    if (sl == 8) {
        if (threadIdx.x < 32)
            head_buf[g*96 + l*32 + i] = h[(size_t)head_ids[g]*32 + i];
        else if (threadIdx.x < 64)
            tail_buf[g*96 + l*32 + i] = h[(size_t)tail_ids[g]*32 + i];
        return;
    }
    int sub = threadIdx.x >> 5;
    float acc = 0.f;
    for (int k = sub; k < 125; k += 8)
        acc += h[((size_t)g*NPER + sl*125 + k)*32 + i];
    __shared__ float red[8][32];
    red[sub][i] = acc;
    __syncthreads();
    if (threadIdx.x < 32) {
        float s2 = 0.f;
        #pragma unroll
        for (int k = 0; k < 8; k++) s2 += red[k][threadIdx.x];
        atomicAdd(&g_acc[g*96 + l*32 + threadIdx.x], s2 * (1.0f/NPER));
    }
}

// ==================== final readout ====================
__global__ __launch_bounds__(64) void readout_k(
    const float* __restrict__ g_acc, const float* __restrict__ head_buf,
    const float* __restrict__ tail_buf, const float* __restrict__ rel_tab,
    const int* __restrict__ rel_labels, const float* __restrict__ fc_w,
    const float* __restrict__ fc_b, float* __restrict__ out)
{
    int g = blockIdx.x;
    int t = threadIdx.x;
    float s = 0.f;
    for (int idx = t; idx < 320; idx += 64) {
        float v;
        if (idx < 96)       v = g_acc[g*96 + idx];
        else if (idx < 192) v = head_buf[g*96 + idx - 96];
        else if (idx < 288) v = tail_buf[g*96 + idx - 192];
        else                v = rel_tab[rel_labels[g]*32 + (idx - 288)];
        s += v * fc_w[idx];
    }
    s += __shfl_xor(s, 1, 64);
    s += __shfl_xor(s, 2, 64);
    s += __shfl_xor(s, 4, 64);
    s += __shfl_xor(s, 8, 64);
    s += __shfl_xor(s, 16, 64);
    s += __shfl_xor(s, 32, 64);
    if (t == 0) out[g] = s + fc_b[0];
}

extern "C" void kernel_launch(void* const* d_in, const int* in_sizes, int n_in,
                              void* d_out, int out_size, void* d_ws, size_t ws_size,
                              hipStream_t stream) {
    const float* feat        = (const float*)d_in[0];
    const float* basis       = (const float*)d_in[1];   // [3,4,32,32]
    const float* w_comp      = (const float*)d_in[2];   // [3,200,4]
    const float* self_loop_w = (const float*)d_in[3];   // [3,32,32]
    const float* A_w         = (const float*)d_in[4];   // [3,128,32]
    const float* A_b         = (const float*)d_in[5];   // [3,32]
    const float* B_w         = (const float*)d_in[6];   // [3,32,1]
    const float* B_b         = (const float*)d_in[7];   // [3,1]
    const float* attn_tab    = (const float*)d_in[8];   // [200,32]
    const float* rel_tab     = (const float*)d_in[9];   // [200,32]
    const float* fc_w        = (const float*)d_in[10];  // [320,1]
    const float* fc_b        = (const float*)d_in[11];  // [1]
    const int* src        = (const int*)d_in[12];
    const int* dst        = (const int*)d_in[13];
    const int* etype      = (const int*)d_in[14];
    const int* elabel     = (const int*)d_in[15];
    const int* head_ids   = (const int*)d_in[17];
    const int* tail_ids   = (const int*)d_in[18];
    const int* rel_labels = (const int*)d_in[19];

    float* ws = (float*)d_ws;
    size_t off = 0;
    float* h0    = ws + off; off += (size_t)NNODES * 32;
    float* h1    = ws + off; off += (size_t)NNODES * 32;
    float* xproj = ws + off; off += (size_t)NNODES * 128;
    float* psrc  = ws + off; off += (size_t)NNODES * 32;
    float* pdst  = ws + off; off += (size_t)NNODES * 32;
    float* selfp = ws + off; off += (size_t)NNODES * 32;
    float* t1    = ws + off; off += 200 * 32;
    float* t2    = ws + off; off += 200 * 32;
    float* g_acc    = ws + off; off += NGRAPH * 96;
    float* head_buf = ws + off; off += NGRAPH * 96;
    float* tail_buf = ws + off; off += NGRAPH * 96;
    int* count  = (int*)(ws + off); off += NNODES;
    int* offs   = (int*)(ws + off); off += NNODES;
    int* cursor = (int*)(ws + off); off += NNODES;
    off = (off + 3) & ~(size_t)3;               // 16 B align
    int4* sorted = (int4*)(ws + off); off += (size_t)NEDGES * 4;

    // ---- one-time per call: CSR by dst + zero mean accumulator ----
    zero_int_k<<<(NNODES + 255)/256, 256, 0, stream>>>(count, NNODES);
    zero_float_k<<<(NGRAPH*96 + 255)/256, 256, 0, stream>>>(g_acc, NGRAPH*96);
    hist_k<<<(NEDGES + 255)/256, 256, 0, stream>>>(dst, count);
    scan_k<<<NGRAPH, 1024, 0, stream>>>(count, offs, cursor);
    scatter_k<<<(NEDGES + 255)/256, 256, 0, stream>>>(src, dst, etype, elabel,
                                                      cursor, sorted);

    const float* hcur = feat;
    float* hbufs[2] = { h0, h1 };
    for (int l = 0; l < 3; l++) {
        node2_k<<<(NNODES + 511)/512, 256, 0, stream>>>(
            hcur, basis + (size_t)l*4096, self_loop_w + (size_t)l*1024,
            A_w + (size_t)l*4096, xproj, psrc, pdst, selfp);
        rel_tables_k<<<200, 64, 0, stream>>>(
            attn_tab, A_w + (size_t)l*4096, A_b + (size_t)l*32, t1, t2);
        float* hn = hbufs[l & 1];
        edge_csr_k<<<NNODES/4, 256, 0, stream>>>(
            sorted, offs, psrc, pdst, t1, t2, xproj, selfp,
            w_comp + (size_t)l*800, B_w + (size_t)l*32, B_b + l, hn);
        dim3 mgrid(NGRAPH, 9);
        mean_ht_k<<<mgrid, 256, 0, stream>>>(
            hn, head_ids, tail_ids, g_acc, head_buf, tail_buf, l);
        hcur = hn;
    }
    readout_k<<<NGRAPH, 64, 0, stream>>>(
        g_acc, head_buf, tail_buf, rel_tab, rel_labels, fc_w, fc_b, (float*)d_out);
}

// Round 8
// 714.826 us; speedup vs baseline: 2.7061x; 2.7061x over previous
//
#include <hip/hip_runtime.h>

#define NGRAPH 100
#define NPER   1000
#define NNODES 100000
#define NEDGES 1600000
#define EPG    16000   // edges per graph

// ==================== small utility kernels ====================
__global__ __launch_bounds__(256) void zero_int_k(int* __restrict__ p, int n) {
    int i = blockIdx.x * 256 + threadIdx.x;
    if (i < n) p[i] = 0;
}
__global__ __launch_bounds__(256) void zero_float_k(float* __restrict__ p, int n) {
    int i = blockIdx.x * 256 + threadIdx.x;
    if (i < n) p[i] = 0.f;
}

// ==================== counting sort of edges by DST ====================
__global__ __launch_bounds__(256) void hist_k(const int* __restrict__ dst,
                                              int* __restrict__ count) {
    int e = blockIdx.x * 256 + threadIdx.x;
    if (e < NEDGES) atomicAdd(&count[dst[e]], 1);
}

__global__ __launch_bounds__(1024) void scan_k(const int* __restrict__ count,
                                               int* __restrict__ offs,
                                               int* __restrict__ cursor) {
    __shared__ int sc[1024];
    int t = threadIdx.x, g = blockIdx.x;
    int v = (t < NPER) ? count[g * NPER + t] : 0;
    sc[t] = v;
    __syncthreads();
    for (int s = 1; s < 1024; s <<= 1) {
        int add = (t >= s) ? sc[t - s] : 0;
        __syncthreads();
        sc[t] += add;
        __syncthreads();
    }
    if (t < NPER) {
        int start = g * EPG + sc[t] - v;   // exclusive
        offs[g * NPER + t]   = start;
        cursor[g * NPER + t] = start;
    }
}

// stores pre-scaled indices: {src*32, etype*32, elabel*32, etype*4}
__global__ __launch_bounds__(256) void scatter_k(
    const int* __restrict__ src, const int* __restrict__ dst,
    const int* __restrict__ et, const int* __restrict__ el,
    int* __restrict__ cursor, int4* __restrict__ sorted) {
    int e = blockIdx.x * 256 + threadIdx.x;
    if (e >= NEDGES) return;
    int d = dst[e];
    int p = atomicAdd(&cursor[d], 1);
    int et_ = et[e];
    sorted[p] = make_int4(src[e] * 32, et_ * 32, el[e] * 32, et_ * 4);
}

// ==================== fused node projections, 2 nodes/thread ===============
// __launch_bounds__(256,4): force <=128 VGPR (4 waves/EU) so the scheduler
// cannot hoist unbounded ds_read results (R6/R7 lesson: 256 VGPR + 1 GB
// scratch traffic). #pragma unroll 4 on d-loops caps in-flight weight loads.
__global__ __launch_bounds__(256, 4) void node2_k(
    const float* __restrict__ h, const float* __restrict__ basis_l,
    const float* __restrict__ selfw_l, const float* __restrict__ Aw_l,
    float* __restrict__ xproj, float* __restrict__ psrc,
    float* __restrict__ pdst, float* __restrict__ selfp)
{
    __shared__ float w_s[7168]; // [0,4096) basis, [4096,5120) selfw, [5120,7168) A1|A2
    {
        const float4* b4 = (const float4*)basis_l;  // 1024
        const float4* s4 = (const float4*)selfw_l;  // 256
        const float4* a4 = (const float4*)Aw_l;     // 512 (rows 0..63)
        float4* w4 = (float4*)w_s;
        for (int k = threadIdx.x; k < 1792; k += 256) {
            float4 v;
            if (k < 1024)      v = b4[k];
            else if (k < 1280) v = s4[k - 1024];
            else               v = a4[k - 1280];
            w4[k] = v;
        }
    }
    __syncthreads();

    const int nA = blockIdx.x * 512 + threadIdx.x;
    const int nB = nA + 256;
    const bool vA = (nA < NNODES);
    const bool vB = (nB < NNODES);
    const int lA = vA ? nA : 0;
    const int lB = vB ? nB : 0;

    float hA[32], hB[32];
    {
        const float4* hpA = (const float4*)(h + (size_t)lA * 32);
        const float4* hpB = (const float4*)(h + (size_t)lB * 32);
        #pragma unroll
        for (int k = 0; k < 8; k++) {
            float4 a = hpA[k], b = hpB[k];
            hA[4*k+0]=a.x; hA[4*k+1]=a.y; hA[4*k+2]=a.z; hA[4*k+3]=a.w;
            hB[4*k+0]=b.x; hB[4*k+1]=b.y; hB[4*k+2]=b.z; hB[4*k+3]=b.w;
        }
    }

    float* xoutA = xproj + (size_t)lA * 128;
    float* xoutB = xproj + (size_t)lB * 128;

    #pragma unroll 1
    for (int oc = 0; oc < 8; oc++) {
        // ---- basis: 4 matrices -> transpose-packed b-minor xproj ----
        {
            float4 pA[4], pB[4];
            #pragma unroll 1
            for (int b = 0; b < 4; b++) {
                const float* wb = w_s + b * 1024 + oc * 4;
                float4 a = {0.f,0.f,0.f,0.f}, c = {0.f,0.f,0.f,0.f};
                #pragma unroll 4
                for (int d = 0; d < 32; d++) {
                    float4 wv = *(const float4*)(wb + d * 32);
                    a.x = fmaf(hA[d], wv.x, a.x);  c.x = fmaf(hB[d], wv.x, c.x);
                    a.y = fmaf(hA[d], wv.y, a.y);  c.y = fmaf(hB[d], wv.y, c.y);
                    a.z = fmaf(hA[d], wv.z, a.z);  c.z = fmaf(hB[d], wv.z, c.z);
                    a.w = fmaf(hA[d], wv.w, a.w);  c.w = fmaf(hB[d], wv.w, c.w);
                }
                pA[b] = a; pB[b] = c;
            }
            if (vA) {
                *(float4*)(xoutA + (oc*4+0)*4) = make_float4(pA[0].x,pA[1].x,pA[2].x,pA[3].x);
                *(float4*)(xoutA + (oc*4+1)*4) = make_float4(pA[0].y,pA[1].y,pA[2].y,pA[3].y);
                *(float4*)(xoutA + (oc*4+2)*4) = make_float4(pA[0].z,pA[1].z,pA[2].z,pA[3].z);
                *(float4*)(xoutA + (oc*4+3)*4) = make_float4(pA[0].w,pA[1].w,pA[2].w,pA[3].w);
            }
            if (vB) {
                *(float4*)(xoutB + (oc*4+0)*4) = make_float4(pB[0].x,pB[1].x,pB[2].x,pB[3].x);
                *(float4*)(xoutB + (oc*4+1)*4) = make_float4(pB[0].y,pB[1].y,pB[2].y,pB[3].y);
                *(float4*)(xoutB + (oc*4+2)*4) = make_float4(pB[0].z,pB[1].z,pB[2].z,pB[3].z);
                *(float4*)(xoutB + (oc*4+3)*4) = make_float4(pB[0].w,pB[1].w,pB[2].w,pB[3].w);
            }
        }
        // ---- A1 -> psrc, A2 -> pdst, selfw -> selfp ----
        #pragma unroll 1
        for (int m = 0; m < 3; m++) {
            const float* wb = w_s + (m == 0 ? 5120 : m == 1 ? 6144 : 4096) + oc * 4;
            float* outp = (m == 0 ? psrc : m == 1 ? pdst : selfp);
            float4 a = {0.f,0.f,0.f,0.f}, c = {0.f,0.f,0.f,0.f};
            #pragma unroll 4
            for (int d = 0; d < 32; d++) {
                float4 wv = *(const float4*)(wb + d * 32);
                a.x = fmaf(hA[d], wv.x, a.x);  c.x = fmaf(hB[d], wv.x, c.x);
                a.y = fmaf(hA[d], wv.y, a.y);  c.y = fmaf(hB[d], wv.y, c.y);
                a.z = fmaf(hA[d], wv.z, a.z);  c.z = fmaf(hB[d], wv.z, c.z);
                a.w = fmaf(hA[d], wv.w, a.w);  c.w = fmaf(hB[d], wv.w, c.w);
            }
            if (vA) *(float4*)(outp + (size_t)lA*32 + oc*4) = a;
            if (vB) *(float4*)(outp + (size_t)lB*32 + oc*4) = c;
        }
    }
}

// ==================== per-relation attention tables ====================
__global__ __launch_bounds__(64) void rel_tables_k(
    const float* __restrict__ attn_tab, const float* __restrict__ Aw_l,
    const float* __restrict__ Ab_l, float* __restrict__ t1, float* __restrict__ t2)
{
    int r = blockIdx.x;
    int t = threadIdx.x;
    int o = t & 31;
    bool second = t >= 32;
    const float* at = attn_tab + r * 32;
    const float* W  = Aw_l + (second ? 96*32 : 64*32);
    float acc = second ? 0.f : Ab_l[o];
    #pragma unroll
    for (int d = 0; d < 32; d++) acc += at[d] * W[d*32 + o];
    (second ? t2 : t1)[r*32 + o] = acc;
}

// ==================== CSR edge kernel: 1 wave/node, 4 edges/iter ===========
__global__ __launch_bounds__(256) void edge_csr_k(
    const int4* __restrict__ sorted, const int* __restrict__ offs,
    const float* __restrict__ psrc, const float* __restrict__ pdst,
    const float* __restrict__ t1,   const float* __restrict__ t2,
    const float* __restrict__ xproj, const float* __restrict__ selfp,
    const float* __restrict__ wcomp_l,
    const float* __restrict__ Bw, const float* __restrict__ Bb,
    float* __restrict__ h_next)
{
    // XCD-bijective swizzle: 25000 blocks, 25000 % 8 == 0.
    const int CPX = 25000 / 8;
    int bid = (int)blockIdx.x;
    bid = (bid % 8) * CPX + bid / 8;

    const int wib  = threadIdx.x >> 6;   // wave in block: 0..3
    const int lane = threadIdx.x & 63;
    const int p    = lane >> 5;          // edge of pair
    const int i    = lane & 31;          // channel
    const int n    = bid * 4 + wib;      // dst node

    const int start = offs[n];
    const int end   = (n == NNODES - 1) ? NEDGES : offs[n + 1];
    const float bw = Bw[i];
    const float bb = Bb[0];
    const float pd = pdst[(size_t)n * 32 + i];

    float acc0 = 0.f, acc1 = 0.f;
    for (int e0 = start; e0 < end; e0 += 4) {
        int ea = e0 + p;
        int eb = e0 + 2 + p;
        bool va = (ea < end);
        bool vb = (eb < end);
        int4 eda = sorted[va ? ea : e0];      // {s*32, et*32, el*32, et*4}
        int4 edb = sorted[vb ? eb : e0];
        int ta = eda.x + i;
        int tb = edb.x + i;
        float psa = psrc[ta];
        float psb = psrc[tb];
        float4 xva = *(const float4*)(xproj + (size_t)ta * 4);
        float4 xvb = *(const float4*)(xproj + (size_t)tb * 4);
        float t1a = t1[eda.y + i], t1b = t1[edb.y + i];
        float t2a = t2[eda.z + i], t2b = t2[edb.z + i];
        float4 ca = *(const float4*)(wcomp_l + eda.w);
        float4 cb = *(const float4*)(wcomp_l + edb.w);

        float za = fmaxf(psa + pd + t1a + t2a, 0.f);
        float zb = fmaxf(psb + pd + t1b + t2b, 0.f);
        float pa = za * bw, pb = zb * bw;
        pa += __shfl_xor(pa, 1, 32);   pb += __shfl_xor(pb, 1, 32);
        pa += __shfl_xor(pa, 2, 32);   pb += __shfl_xor(pb, 2, 32);
        pa += __shfl_xor(pa, 4, 32);   pb += __shfl_xor(pb, 4, 32);
        pa += __shfl_xor(pa, 8, 32);   pb += __shfl_xor(pb, 8, 32);
        pa += __shfl_xor(pa, 16, 32);  pb += __shfl_xor(pb, 16, 32);
        float aa = __builtin_amdgcn_rcpf(1.f + __expf(-(pa + bb)));
        float ab = __builtin_amdgcn_rcpf(1.f + __expf(-(pb + bb)));
        aa = va ? aa : 0.f;
        ab = vb ? ab : 0.f;
        float msga = ca.x*xva.x + ca.y*xva.y + ca.z*xva.z + ca.w*xva.w;
        float msgb = cb.x*xvb.x + cb.y*xvb.y + cb.z*xvb.z + cb.w*xvb.w;
        acc0 = fmaf(aa, msga, acc0);
        acc1 = fmaf(ab, msgb, acc1);
    }
    float acc = acc0 + acc1;
    acc += __shfl_xor(acc, 32, 64);      // combine the two edge-halves
    if (p == 0) {
        float hv = fmaxf(acc + selfp[(size_t)n*32 + i], 0.f);
        h_next[(size_t)n*32 + i] = hv;
    }
}

// ==================== per-graph mean (8 slices) + head/tail (y=8) ==========
__global__ __launch_bounds__(256) void mean_ht_k(
    const float* __restrict__ h, const int* __restrict__ head_ids,
    const int* __restrict__ tail_ids, float* __restrict__ g_acc,
    float* __restrict__ head_buf, float* __restrict__ tail_buf, int l)
{
    int g  = blockIdx.x;
    int sl = blockIdx.y;
    int i  = threadIdx.x & 31;
    if (sl == 8) {
        if (threadIdx.x < 32)
            head_buf[g*96 + l*32 + i] = h[(size_t)head_ids[g]*32 + i];
        else if (threadIdx.x < 64)
            tail_buf[g*96 + l*32 + i] = h[(size_t)tail_ids[g]*32 + i];
        return;
    }
    int sub = threadIdx.x >> 5;
    float acc = 0.f;
    for (int k = sub; k < 125; k += 8)
        acc += h[((size_t)g*NPER + sl*125 + k)*32 + i];
    __shared__ float red[8][32];
    red[sub][i] = acc;
    __syncthreads();
    if (threadIdx.x < 32) {
        float s2 = 0.f;
        #pragma unroll
        for (int k = 0; k < 8; k++) s2 += red[k][threadIdx.x];
        atomicAdd(&g_acc[g*96 + l*32 + threadIdx.x], s2 * (1.0f/NPER));
    }
}

// ==================== final readout ====================
__global__ __launch_bounds__(64) void readout_k(
    const float* __restrict__ g_acc, const float* __restrict__ head_buf,
    const float* __restrict__ tail_buf, const float* __restrict__ rel_tab,
    const int* __restrict__ rel_labels, const float* __restrict__ fc_w,
    const float* __restrict__ fc_b, float* __restrict__ out)
{
    int g = blockIdx.x;
    int t = threadIdx.x;
    float s = 0.f;
    for (int idx = t; idx < 320; idx += 64) {
        float v;
        if (idx < 96)       v = g_acc[g*96 + idx];
        else if (idx < 192) v = head_buf[g*96 + idx - 96];
        else if (idx < 288) v = tail_buf[g*96 + idx - 192];
        else                v = rel_tab[rel_labels[g]*32 + (idx - 288)];
        s += v * fc_w[idx];
    }
    s += __shfl_xor(s, 1, 64);
    s += __shfl_xor(s, 2, 64);
    s += __shfl_xor(s, 4, 64);
    s += __shfl_xor(s, 8, 64);
    s += __shfl_xor(s, 16, 64);
    s += __shfl_xor(s, 32, 64);
    if (t == 0) out[g] = s + fc_b[0];
}

extern "C" void kernel_launch(void* const* d_in, const int* in_sizes, int n_in,
                              void* d_out, int out_size, void* d_ws, size_t ws_size,
                              hipStream_t stream) {
    const float* feat        = (const float*)d_in[0];
    const float* basis       = (const float*)d_in[1];   // [3,4,32,32]
    const float* w_comp      = (const float*)d_in[2];   // [3,200,4]
    const float* self_loop_w = (const float*)d_in[3];   // [3,32,32]
    const float* A_w         = (const float*)d_in[4];   // [3,128,32]
    const float* A_b         = (const float*)d_in[5];   // [3,32]
    const float* B_w         = (const float*)d_in[6];   // [3,32,1]
    const float* B_b         = (const float*)d_in[7];   // [3,1]
    const float* attn_tab    = (const float*)d_in[8];   // [200,32]
    const float* rel_tab     = (const float*)d_in[9];   // [200,32]
    const float* fc_w        = (const float*)d_in[10];  // [320,1]
    const float* fc_b        = (const float*)d_in[11];  // [1]
    const int* src        = (const int*)d_in[12];
    const int* dst        = (const int*)d_in[13];
    const int* etype      = (const int*)d_in[14];
    const int* elabel     = (const int*)d_in[15];
    const int* head_ids   = (const int*)d_in[17];
    const int* tail_ids   = (const int*)d_in[18];
    const int* rel_labels = (const int*)d_in[19];

    float* ws = (float*)d_ws;
    size_t off = 0;
    float* h0    = ws + off; off += (size_t)NNODES * 32;
    float* h1    = ws + off; off += (size_t)NNODES * 32;
    float* xproj = ws + off; off += (size_t)NNODES * 128;
    float* psrc  = ws + off; off += (size_t)NNODES * 32;
    float* pdst  = ws + off; off += (size_t)NNODES * 32;
    float* selfp = ws + off; off += (size_t)NNODES * 32;
    float* t1    = ws + off; off += 200 * 32;
    float* t2    = ws + off; off += 200 * 32;
    float* g_acc    = ws + off; off += NGRAPH * 96;
    float* head_buf = ws + off; off += NGRAPH * 96;
    float* tail_buf = ws + off; off += NGRAPH * 96;
    int* count  = (int*)(ws + off); off += NNODES;
    int* offs   = (int*)(ws + off); off += NNODES;
    int* cursor = (int*)(ws + off); off += NNODES;
    off = (off + 3) & ~(size_t)3;               // 16 B align
    int4* sorted = (int4*)(ws + off); off += (size_t)NEDGES * 4;

    // ---- one-time per call: CSR by dst + zero mean accumulator ----
    zero_int_k<<<(NNODES + 255)/256, 256, 0, stream>>>(count, NNODES);
    zero_float_k<<<(NGRAPH*96 + 255)/256, 256, 0, stream>>>(g_acc, NGRAPH*96);
    hist_k<<<(NEDGES + 255)/256, 256, 0, stream>>>(dst, count);
    scan_k<<<NGRAPH, 1024, 0, stream>>>(count, offs, cursor);
    scatter_k<<<(NEDGES + 255)/256, 256, 0, stream>>>(src, dst, etype, elabel,
                                                      cursor, sorted);

    const float* hcur = feat;
    float* hbufs[2] = { h0, h1 };
    for (int l = 0; l < 3; l++) {
        node2_k<<<(NNODES + 511)/512, 256, 0, stream>>>(
            hcur, basis + (size_t)l*4096, self_loop_w + (size_t)l*1024,
            A_w + (size_t)l*4096, xproj, psrc, pdst, selfp);
        rel_tables_k<<<200, 64, 0, stream>>>(
            attn_tab, A_w + (size_t)l*4096, A_b + (size_t)l*32, t1, t2);
        float* hn = hbufs[l & 1];
        edge_csr_k<<<NNODES/4, 256, 0, stream>>>(
            sorted, offs, psrc, pdst, t1, t2, xproj, selfp,
            w_comp + (size_t)l*800, B_w + (size_t)l*32, B_b + l, hn);
        dim3 mgrid(NGRAPH, 9);
        mean_ht_k<<<mgrid, 256, 0, stream>>>(
            hn, head_ids, tail_ids, g_acc, head_buf, tail_buf, l);
        hcur = hn;
    }
    readout_k<<<NGRAPH, 64, 0, stream>>>(
        g_acc, head_buf, tail_buf, rel_tab, rel_labels, fc_w, fc_b, (float*)d_out);
}

// Round 9
// 624.193 us; speedup vs baseline: 3.0991x; 1.1452x over previous
//
#include <hip/hip_runtime.h>

#define NGRAPH 100
#define NPER   1000
#define NNODES 100000
#define NEDGES 1600000
#define EPG    16000   // edges per graph

// ==================== small utility kernels ====================
__global__ __launch_bounds__(256) void zero_int_k(int* __restrict__ p, int n) {
    int i = blockIdx.x * 256 + threadIdx.x;
    if (i < n) p[i] = 0;
}
__global__ __launch_bounds__(256) void zero_float_k(float* __restrict__ p, int n) {
    int i = blockIdx.x * 256 + threadIdx.x;
    if (i < n) p[i] = 0.f;
}

// ==================== counting sort of edges by DST ====================
__global__ __launch_bounds__(256) void hist_k(const int* __restrict__ dst,
                                              int* __restrict__ count) {
    int e = blockIdx.x * 256 + threadIdx.x;
    if (e < NEDGES) atomicAdd(&count[dst[e]], 1);
}

__global__ __launch_bounds__(1024) void scan_k(const int* __restrict__ count,
                                               int* __restrict__ offs,
                                               int* __restrict__ cursor) {
    __shared__ int sc[1024];
    int t = threadIdx.x, g = blockIdx.x;
    int v = (t < NPER) ? count[g * NPER + t] : 0;
    sc[t] = v;
    __syncthreads();
    for (int s = 1; s < 1024; s <<= 1) {
        int add = (t >= s) ? sc[t - s] : 0;
        __syncthreads();
        sc[t] += add;
        __syncthreads();
    }
    if (t < NPER) {
        int start = g * EPG + sc[t] - v;   // exclusive
        offs[g * NPER + t]   = start;
        cursor[g * NPER + t] = start;
    }
}

// stores pre-scaled indices: {src*32, etype*32, elabel*32, etype*4}
__global__ __launch_bounds__(256) void scatter_k(
    const int* __restrict__ src, const int* __restrict__ dst,
    const int* __restrict__ et, const int* __restrict__ el,
    int* __restrict__ cursor, int4* __restrict__ sorted) {
    int e = blockIdx.x * 256 + threadIdx.x;
    if (e >= NEDGES) return;
    int d = dst[e];
    int p = atomicAdd(&cursor[d], 1);
    int et_ = et[e];
    sorted[p] = make_int4(src[e] * 32, et_ * 32, el[e] * 32, et_ * 4);
}

// ==================== node projections: channel-sliced, 1 node/thread ======
// grid (391, 6). y=0..3: xproj channels [y*8, y*8+8) -> 128B contiguous per
// node (full lines, one thread). y=4,5: psrc/pdst/selfp channel halves
// [(y-4)*16, +16) -> one full 64B line per matrix per thread.
// R8 lessons: __launch_bounds__(256,4) caps VGPR (no spill); unroll 4 caps
// in-flight ds_reads; high block count (2346) gives the TLP that 2-node
// (196 blocks, 1 wave/EU) lacked.
__global__ __launch_bounds__(256, 4) void node_k(
    const float* __restrict__ h, const float* __restrict__ basis_l,
    const float* __restrict__ selfw_l, const float* __restrict__ Aw_l,
    float* __restrict__ xproj, float* __restrict__ psrc,
    float* __restrict__ pdst, float* __restrict__ selfp)
{
    const int y = blockIdx.y;
    __shared__ float w_s[4096];
    if (y < 4) {
        const float4* b4 = (const float4*)basis_l;   // 1024 float4
        float4* w4 = (float4*)w_s;
        for (int k = threadIdx.x; k < 1024; k += 256) w4[k] = b4[k];
    } else {
        const float4* a4 = (const float4*)Aw_l;      // 512 float4 (rows 0..63)
        const float4* s4 = (const float4*)selfw_l;   // 256 float4
        float4* w4 = (float4*)w_s;
        for (int k = threadIdx.x; k < 768; k += 256)
            w4[k] = (k < 512) ? a4[k] : s4[k - 512];
    }
    __syncthreads();

    int n = blockIdx.x * 256 + threadIdx.x;
    if (n >= NNODES) return;

    float hreg[32];
    {
        const float4* hp = (const float4*)(h + (size_t)n * 32);
        #pragma unroll
        for (int k = 0; k < 8; k++) {
            float4 v = hp[k];
            hreg[4*k+0]=v.x; hreg[4*k+1]=v.y; hreg[4*k+2]=v.z; hreg[4*k+3]=v.w;
        }
    }

    if (y < 4) {
        // two output channels groups oc = y*2, y*2+1 -> xproj[n*128 + y*32 ..)
        float* xout = xproj + (size_t)n * 128 + y * 32;
        #pragma unroll 1
        for (int ocl = 0; ocl < 2; ocl++) {
            const int oc = y * 2 + ocl;
            float4 p[4];
            #pragma unroll 1
            for (int b = 0; b < 4; b++) {
                const float* wb = w_s + b * 1024 + oc * 4;
                float4 a = {0.f,0.f,0.f,0.f};
                #pragma unroll 4
                for (int d = 0; d < 32; d++) {
                    float4 wv = *(const float4*)(wb + d * 32);
                    a.x = fmaf(hreg[d], wv.x, a.x);
                    a.y = fmaf(hreg[d], wv.y, a.y);
                    a.z = fmaf(hreg[d], wv.z, a.z);
                    a.w = fmaf(hreg[d], wv.w, a.w);
                }
                p[b] = a;
            }
            // b-minor transpose pack: 4 float4 = 64B contiguous
            float* o = xout + ocl * 16;
            *(float4*)(o +  0) = make_float4(p[0].x, p[1].x, p[2].x, p[3].x);
            *(float4*)(o +  4) = make_float4(p[0].y, p[1].y, p[2].y, p[3].y);
            *(float4*)(o +  8) = make_float4(p[0].z, p[1].z, p[2].z, p[3].z);
            *(float4*)(o + 12) = make_float4(p[0].w, p[1].w, p[2].w, p[3].w);
        }
    } else {
        // channel half [oc0*4, oc0*4+16) of psrc/pdst/selfp
        const int oc0 = (y - 4) * 4;
        #pragma unroll 1
        for (int m = 0; m < 3; m++) {
            const float* wbase = w_s + (m < 2 ? m * 1024 : 2048);
            float* outp = (m == 0 ? psrc : m == 1 ? pdst : selfp);
            float4 r[4];
            #pragma unroll 1
            for (int ocl = 0; ocl < 4; ocl++) {
                const float* wb = wbase + (oc0 + ocl) * 4;
                float4 a = {0.f,0.f,0.f,0.f};
                #pragma unroll 4
                for (int d = 0; d < 32; d++) {
                    float4 wv = *(const float4*)(wb + d * 32);
                    a.x = fmaf(hreg[d], wv.x, a.x);
                    a.y = fmaf(hreg[d], wv.y, a.y);
                    a.z = fmaf(hreg[d], wv.z, a.z);
                    a.w = fmaf(hreg[d], wv.w, a.w);
                }
                r[ocl] = a;
            }
            float* o = outp + (size_t)n * 32 + oc0 * 4;   // 64B line
            *(float4*)(o +  0) = r[0];
            *(float4*)(o +  4) = r[1];
            *(float4*)(o +  8) = r[2];
            *(float4*)(o + 12) = r[3];
        }
    }
}

// ==================== per-relation attention tables ====================
__global__ __launch_bounds__(64) void rel_tables_k(
    const float* __restrict__ attn_tab, const float* __restrict__ Aw_l,
    const float* __restrict__ Ab_l, float* __restrict__ t1, float* __restrict__ t2)
{
    int r = blockIdx.x;
    int t = threadIdx.x;
    int o = t & 31;
    bool second = t >= 32;
    const float* at = attn_tab + r * 32;
    const float* W  = Aw_l + (second ? 96*32 : 64*32);
    float acc = second ? 0.f : Ab_l[o];
    #pragma unroll
    for (int d = 0; d < 32; d++) acc += at[d] * W[d*32 + o];
    (second ? t2 : t1)[r*32 + o] = acc;
}

// ==================== CSR edge kernel: 1 wave/node, 4 edges/iter ===========
__global__ __launch_bounds__(256) void edge_csr_k(
    const int4* __restrict__ sorted, const int* __restrict__ offs,
    const float* __restrict__ psrc, const float* __restrict__ pdst,
    const float* __restrict__ t1,   const float* __restrict__ t2,
    const float* __restrict__ xproj, const float* __restrict__ selfp,
    const float* __restrict__ wcomp_l,
    const float* __restrict__ Bw, const float* __restrict__ Bb,
    float* __restrict__ h_next)
{
    // XCD-bijective swizzle: 25000 blocks, 25000 % 8 == 0.
    const int CPX = 25000 / 8;
    int bid = (int)blockIdx.x;
    bid = (bid % 8) * CPX + bid / 8;

    const int wib  = threadIdx.x >> 6;   // wave in block: 0..3
    const int lane = threadIdx.x & 63;
    const int p    = lane >> 5;          // edge of pair
    const int i    = lane & 31;          // channel
    const int n    = bid * 4 + wib;      // dst node

    const int start = offs[n];
    const int end   = (n == NNODES - 1) ? NEDGES : offs[n + 1];
    const float bw = Bw[i];
    const float bb = Bb[0];
    const float pd = pdst[(size_t)n * 32 + i];

    float acc0 = 0.f, acc1 = 0.f;
    for (int e0 = start; e0 < end; e0 += 4) {
        int ea = e0 + p;
        int eb = e0 + 2 + p;
        bool va = (ea < end);
        bool vb = (eb < end);
        int4 eda = sorted[va ? ea : e0];      // {s*32, et*32, el*32, et*4}
        int4 edb = sorted[vb ? eb : e0];
        int ta = eda.x + i;
        int tb = edb.x + i;
        float psa = psrc[ta];
        float psb = psrc[tb];
        float4 xva = *(const float4*)(xproj + (size_t)ta * 4);
        float4 xvb = *(const float4*)(xproj + (size_t)tb * 4);
        float t1a = t1[eda.y + i], t1b = t1[edb.y + i];
        float t2a = t2[eda.z + i], t2b = t2[edb.z + i];
        float4 ca = *(const float4*)(wcomp_l + eda.w);
        float4 cb = *(const float4*)(wcomp_l + edb.w);

        float za = fmaxf(psa + pd + t1a + t2a, 0.f);
        float zb = fmaxf(psb + pd + t1b + t2b, 0.f);
        float pa = za * bw, pb = zb * bw;
        pa += __shfl_xor(pa, 1, 32);   pb += __shfl_xor(pb, 1, 32);
        pa += __shfl_xor(pa, 2, 32);   pb += __shfl_xor(pb, 2, 32);
        pa += __shfl_xor(pa, 4, 32);   pb += __shfl_xor(pb, 4, 32);
        pa += __shfl_xor(pa, 8, 32);   pb += __shfl_xor(pb, 8, 32);
        pa += __shfl_xor(pa, 16, 32);  pb += __shfl_xor(pb, 16, 32);
        float aa = __builtin_amdgcn_rcpf(1.f + __expf(-(pa + bb)));
        float ab = __builtin_amdgcn_rcpf(1.f + __expf(-(pb + bb)));
        aa = va ? aa : 0.f;
        ab = vb ? ab : 0.f;
        float msga = ca.x*xva.x + ca.y*xva.y + ca.z*xva.z + ca.w*xva.w;
        float msgb = cb.x*xvb.x + cb.y*xvb.y + cb.z*xvb.z + cb.w*xvb.w;
        acc0 = fmaf(aa, msga, acc0);
        acc1 = fmaf(ab, msgb, acc1);
    }
    float acc = acc0 + acc1;
    acc += __shfl_xor(acc, 32, 64);      // combine the two edge-halves
    if (p == 0) {
        float hv = fmaxf(acc + selfp[(size_t)n*32 + i], 0.f);
        h_next[(size_t)n*32 + i] = hv;
    }
}

// ==================== per-graph mean (8 slices) + head/tail (y=8) ==========
__global__ __launch_bounds__(256) void mean_ht_k(
    const float* __restrict__ h, const int* __restrict__ head_ids,
    const int* __restrict__ tail_ids, float* __restrict__ g_acc,
    float* __restrict__ head_buf, float* __restrict__ tail_buf, int l)
{
    int g  = blockIdx.x;
    int sl = blockIdx.y;
    int i  = threadIdx.x & 31;
    if (sl == 8) {
        if (threadIdx.x < 32)
            head_buf[g*96 + l*32 + i] = h[(size_t)head_ids[g]*32 + i];
        else if (threadIdx.x < 64)
            tail_buf[g*96 + l*32 + i] = h[(size_t)tail_ids[g]*32 + i];
        return;
    }
    int sub = threadIdx.x >> 5;
    float acc = 0.f;
    for (int k = sub; k < 125; k += 8)
        acc += h[((size_t)g*NPER + sl*125 + k)*32 + i];
    __shared__ float red[8][32];
    red[sub][i] = acc;
    __syncthreads();
    if (threadIdx.x < 32) {
        float s2 = 0.f;
        #pragma unroll
        for (int k = 0; k < 8; k++) s2 += red[k][threadIdx.x];
        atomicAdd(&g_acc[g*96 + l*32 + threadIdx.x], s2 * (1.0f/NPER));
    }
}

// ==================== final readout ====================
__global__ __launch_bounds__(64) void readout_k(
    const float* __restrict__ g_acc, const float* __restrict__ head_buf,
    const float* __restrict__ tail_buf, const float* __restrict__ rel_tab,
    const int* __restrict__ rel_labels, const float* __restrict__ fc_w,
    const float* __restrict__ fc_b, float* __restrict__ out)
{
    int g = blockIdx.x;
    int t = threadIdx.x;
    float s = 0.f;
    for (int idx = t; idx < 320; idx += 64) {
        float v;
        if (idx < 96)       v = g_acc[g*96 + idx];
        else if (idx < 192) v = head_buf[g*96 + idx - 96];
        else if (idx < 288) v = tail_buf[g*96 + idx - 192];
        else                v = rel_tab[rel_labels[g]*32 + (idx - 288)];
        s += v * fc_w[idx];
    }
    s += __shfl_xor(s, 1, 64);
    s += __shfl_xor(s, 2, 64);
    s += __shfl_xor(s, 4, 64);
    s += __shfl_xor(s, 8, 64);
    s += __shfl_xor(s, 16, 64);
    s += __shfl_xor(s, 32, 64);
    if (t == 0) out[g] = s + fc_b[0];
}

extern "C" void kernel_launch(void* const* d_in, const int* in_sizes, int n_in,
                              void* d_out, int out_size, void* d_ws, size_t ws_size,
                              hipStream_t stream) {
    const float* feat        = (const float*)d_in[0];
    const float* basis       = (const float*)d_in[1];   // [3,4,32,32]
    const float* w_comp      = (const float*)d_in[2];   // [3,200,4]
    const float* self_loop_w = (const float*)d_in[3];   // [3,32,32]
    const float* A_w         = (const float*)d_in[4];   // [3,128,32]
    const float* A_b         = (const float*)d_in[5];   // [3,32]
    const float* B_w         = (const float*)d_in[6];   // [3,32,1]
    const float* B_b         = (const float*)d_in[7];   // [3,1]
    const float* attn_tab    = (const float*)d_in[8];   // [200,32]
    const float* rel_tab     = (const float*)d_in[9];   // [200,32]
    const float* fc_w        = (const float*)d_in[10];  // [320,1]
    const float* fc_b        = (const float*)d_in[11];  // [1]
    const int* src        = (const int*)d_in[12];
    const int* dst        = (const int*)d_in[13];
    const int* etype      = (const int*)d_in[14];
    const int* elabel     = (const int*)d_in[15];
    const int* head_ids   = (const int*)d_in[17];
    const int* tail_ids   = (const int*)d_in[18];
    const int* rel_labels = (const int*)d_in[19];

    float* ws = (float*)d_ws;
    size_t off = 0;
    float* h0    = ws + off; off += (size_t)NNODES * 32;
    float* h1    = ws + off; off += (size_t)NNODES * 32;
    float* xproj = ws + off; off += (size_t)NNODES * 128;
    float* psrc  = ws + off; off += (size_t)NNODES * 32;
    float* pdst  = ws + off; off += (size_t)NNODES * 32;
    float* selfp = ws + off; off += (size_t)NNODES * 32;
    float* t1    = ws + off; off += 200 * 32;
    float* t2    = ws + off; off += 200 * 32;
    float* g_acc    = ws + off; off += NGRAPH * 96;
    float* head_buf = ws + off; off += NGRAPH * 96;
    float* tail_buf = ws + off; off += NGRAPH * 96;
    int* count  = (int*)(ws + off); off += NNODES;
    int* offs   = (int*)(ws + off); off += NNODES;
    int* cursor = (int*)(ws + off); off += NNODES;
    off = (off + 3) & ~(size_t)3;               // 16 B align
    int4* sorted = (int4*)(ws + off); off += (size_t)NEDGES * 4;

    // ---- one-time per call: CSR by dst + zero mean accumulator ----
    zero_int_k<<<(NNODES + 255)/256, 256, 0, stream>>>(count, NNODES);
    zero_float_k<<<(NGRAPH*96 + 255)/256, 256, 0, stream>>>(g_acc, NGRAPH*96);
    hist_k<<<(NEDGES + 255)/256, 256, 0, stream>>>(dst, count);
    scan_k<<<NGRAPH, 1024, 0, stream>>>(count, offs, cursor);
    scatter_k<<<(NEDGES + 255)/256, 256, 0, stream>>>(src, dst, etype, elabel,
                                                      cursor, sorted);

    const float* hcur = feat;
    float* hbufs[2] = { h0, h1 };
    for (int l = 0; l < 3; l++) {
        dim3 ngrid((NNODES + 255)/256, 6);
        node_k<<<ngrid, 256, 0, stream>>>(
            hcur, basis + (size_t)l*4096, self_loop_w + (size_t)l*1024,
            A_w + (size_t)l*4096, xproj, psrc, pdst, selfp);
        rel_tables_k<<<200, 64, 0, stream>>>(
            attn_tab, A_w + (size_t)l*4096, A_b + (size_t)l*32, t1, t2);
        float* hn = hbufs[l & 1];
        edge_csr_k<<<NNODES/4, 256, 0, stream>>>(
            sorted, offs, psrc, pdst, t1, t2, xproj, selfp,
            w_comp + (size_t)l*800, B_w + (size_t)l*32, B_b + l, hn);
        dim3 mgrid(NGRAPH, 9);
        mean_ht_k<<<mgrid, 256, 0, stream>>>(
            hn, head_ids, tail_ids, g_acc, head_buf, tail_buf, l);
        hcur = hn;
    }
    readout_k<<<NGRAPH, 64, 0, stream>>>(
        g_acc, head_buf, tail_buf, rel_tab, rel_labels, fc_w, fc_b, (float*)d_out);
}

// Round 10
// 618.224 us; speedup vs baseline: 3.1290x; 1.0097x over previous
//
#include <hip/hip_runtime.h>

#define NGRAPH 100
#define NPER   1000
#define NNODES 100000
#define NEDGES 1600000
#define EPG    16000   // edges per graph

typedef float v2f __attribute__((ext_vector_type(2)));

// ==================== utility: zero count + g_acc in one launch ============
__global__ __launch_bounds__(256) void zero2_k(int* __restrict__ count,
                                               float* __restrict__ g_acc) {
    int i = blockIdx.x * 256 + threadIdx.x;
    if (i < NNODES) count[i] = 0;
    if (i < NGRAPH * 96) g_acc[i] = 0.f;
}

// ==================== counting sort of edges by DST ====================
__global__ __launch_bounds__(256) void hist_k(const int* __restrict__ dst,
                                              int* __restrict__ count) {
    int e = blockIdx.x * 256 + threadIdx.x;
    if (e < NEDGES) atomicAdd(&count[dst[e]], 1);
}

__global__ __launch_bounds__(1024) void scan_k(const int* __restrict__ count,
                                               int* __restrict__ offs,
                                               int* __restrict__ cursor) {
    __shared__ int sc[1024];
    int t = threadIdx.x, g = blockIdx.x;
    int v = (t < NPER) ? count[g * NPER + t] : 0;
    sc[t] = v;
    __syncthreads();
    for (int s = 1; s < 1024; s <<= 1) {
        int add = (t >= s) ? sc[t - s] : 0;
        __syncthreads();
        sc[t] += add;
        __syncthreads();
    }
    if (t < NPER) {
        int start = g * EPG + sc[t] - v;   // exclusive
        offs[g * NPER + t]   = start;
        cursor[g * NPER + t] = start;
    }
}

// stores pre-scaled indices: {src*32, etype*32, elabel*32, etype*4}
__global__ __launch_bounds__(256) void scatter_k(
    const int* __restrict__ src, const int* __restrict__ dst,
    const int* __restrict__ et, const int* __restrict__ el,
    int* __restrict__ cursor, int4* __restrict__ sorted) {
    int e = blockIdx.x * 256 + threadIdx.x;
    if (e >= NEDGES) return;
    int d = dst[e];
    int p = atomicAdd(&cursor[d], 1);
    int et_ = et[e];
    sorted[p] = make_int4(src[e] * 32, et_ * 32, el[e] * 32, et_ * 4);
}

// ==================== node projections: channel-sliced + rel tables ========
// grid (391, 7). y=0..3: xproj channels [y*8,y*8+8) PAIR-PACKED:
//   element (n,c,b) at n*128 + (c>>1)*8 + b*2 + (c&1)  (full 128B/thread)
// y=4,5: psrc/pdst/selfp channel halves (full 64B line per matrix/thread).
// y=6: fused per-relation attention tables t1/t2 (blocks >=50 idle).
__global__ __launch_bounds__(256, 4) void node_k(
    const float* __restrict__ h, const float* __restrict__ basis_l,
    const float* __restrict__ selfw_l, const float* __restrict__ Aw_l,
    const float* __restrict__ Ab_l, const float* __restrict__ attn_tab,
    float* __restrict__ xproj, float* __restrict__ psrc,
    float* __restrict__ pdst, float* __restrict__ selfp,
    float* __restrict__ t1, float* __restrict__ t2)
{
    const int y = blockIdx.y;
    if (y == 6) {   // rel tables: r = bid*4 + wave, 64 threads per r
        int r = blockIdx.x * 4 + (threadIdx.x >> 6);
        if (r >= 200) return;
        int t = threadIdx.x & 63;
        int o = t & 31;
        bool second = t >= 32;
        const float* at = attn_tab + r * 32;
        const float* W  = Aw_l + (second ? 96*32 : 64*32);
        float acc = second ? 0.f : Ab_l[o];
        #pragma unroll 8
        for (int d = 0; d < 32; d++) acc += at[d] * W[d*32 + o];
        (second ? t2 : t1)[r*32 + o] = acc;
        return;
    }

    __shared__ float w_s[4096];
    if (y < 4) {
        const float4* b4 = (const float4*)basis_l;   // 1024 float4
        float4* w4 = (float4*)w_s;
        for (int k = threadIdx.x; k < 1024; k += 256) w4[k] = b4[k];
    } else {
        const float4* a4 = (const float4*)Aw_l;      // 512 float4 (rows 0..63)
        const float4* s4 = (const float4*)selfw_l;   // 256 float4
        float4* w4 = (float4*)w_s;
        for (int k = threadIdx.x; k < 768; k += 256)
            w4[k] = (k < 512) ? a4[k] : s4[k - 512];
    }
    __syncthreads();

    int n = blockIdx.x * 256 + threadIdx.x;
    if (n >= NNODES) return;

    float hreg[32];
    {
        const float4* hp = (const float4*)(h + n * 32);
        #pragma unroll
        for (int k = 0; k < 8; k++) {
            float4 v = hp[k];
            hreg[4*k+0]=v.x; hreg[4*k+1]=v.y; hreg[4*k+2]=v.z; hreg[4*k+3]=v.w;
        }
    }

    if (y < 4) {
        float* xout = xproj + n * 128 + y * 32;
        #pragma unroll 1
        for (int ocl = 0; ocl < 2; ocl++) {
            const int oc = y * 2 + ocl;
            float4 p[4];
            #pragma unroll 1
            for (int b = 0; b < 4; b++) {
                const float* wb = w_s + b * 1024 + oc * 4;
                float4 a = {0.f,0.f,0.f,0.f};
                #pragma unroll 4
                for (int d = 0; d < 32; d++) {
                    float4 wv = *(const float4*)(wb + d * 32);
                    a.x = fmaf(hreg[d], wv.x, a.x);
                    a.y = fmaf(hreg[d], wv.y, a.y);
                    a.z = fmaf(hreg[d], wv.z, a.z);
                    a.w = fmaf(hreg[d], wv.w, a.w);
                }
                p[b] = a;
            }
            // pair-pack: [pair][b][j], 64B contiguous
            float* o = xout + ocl * 16;
            *(float4*)(o +  0) = make_float4(p[0].x, p[0].y, p[1].x, p[1].y);
            *(float4*)(o +  4) = make_float4(p[2].x, p[2].y, p[3].x, p[3].y);
            *(float4*)(o +  8) = make_float4(p[0].z, p[0].w, p[1].z, p[1].w);
            *(float4*)(o + 12) = make_float4(p[2].z, p[2].w, p[3].z, p[3].w);
        }
    } else {
        const int oc0 = (y - 4) * 4;
        #pragma unroll 1
        for (int m = 0; m < 3; m++) {
            const float* wbase = w_s + (m < 2 ? m * 1024 : 2048);
            float* outp = (m == 0 ? psrc : m == 1 ? pdst : selfp);
            float4 r[4];
            #pragma unroll 1
            for (int ocl = 0; ocl < 4; ocl++) {
                const float* wb = wbase + (oc0 + ocl) * 4;
                float4 a = {0.f,0.f,0.f,0.f};
                #pragma unroll 4
                for (int d = 0; d < 32; d++) {
                    float4 wv = *(const float4*)(wb + d * 32);
                    a.x = fmaf(hreg[d], wv.x, a.x);
                    a.y = fmaf(hreg[d], wv.y, a.y);
                    a.z = fmaf(hreg[d], wv.z, a.z);
                    a.w = fmaf(hreg[d], wv.w, a.w);
                }
                r[ocl] = a;
            }
            float* o = outp + n * 32 + oc0 * 4;   // 64B line
            *(float4*)(o +  0) = r[0];
            *(float4*)(o +  4) = r[1];
            *(float4*)(o +  8) = r[2];
            *(float4*)(o + 12) = r[3];
        }
    }
}

// ==================== CSR edge kernel: 16 lanes/edge, 2 ch/lane ============
// wave = 1 node, 4 edge-slots of 16 lanes; packed f32 (v_pk_*) on channel
// pairs; 4-step reduce shared by all 4 edges; int32 SADDR addressing.
__global__ __launch_bounds__(256) void edge_csr_k(
    const int4* __restrict__ sorted, const int* __restrict__ offs,
    const float* __restrict__ psrc, const float* __restrict__ pdst,
    const float* __restrict__ t1,   const float* __restrict__ t2,
    const float* __restrict__ xproj, const float* __restrict__ selfp,
    const float* __restrict__ wcomp_l,
    const float* __restrict__ Bw, const float* __restrict__ Bb,
    float* __restrict__ h_next)
{
    // XCD-bijective swizzle: 25000 blocks, 25000 % 8 == 0.
    const int CPX = 25000 / 8;
    int bid = (int)blockIdx.x;
    bid = (bid % 8) * CPX + bid / 8;

    const int wib  = threadIdx.x >> 6;   // wave in block: 0..3
    const int lane = threadIdx.x & 63;
    const int grp  = lane >> 4;          // edge slot 0..3
    const int ci   = lane & 15;          // channel pair
    const int c2   = ci * 2;
    const int n    = bid * 4 + wib;      // dst node

    const int start = offs[n];
    const int end   = (n == NNODES - 1) ? NEDGES : offs[n + 1];
    const v2f bw = *(const v2f*)(Bw + c2);
    const float bb = Bb[0];
    const v2f pd = *(const v2f*)(pdst + n * 32 + c2);

    v2f acc = {0.f, 0.f};
    for (int e0 = start; e0 < end; e0 += 4) {
        int e = e0 + grp;
        bool valid = (e < end);
        int4 ed = sorted[valid ? e : e0];     // {s*32, et*32, el*32, et*4}
        v2f ps = *(const v2f*)(psrc + ed.x + c2);
        v2f ta = *(const v2f*)(t1 + ed.y + c2);
        v2f tb = *(const v2f*)(t2 + ed.z + c2);
        float4 c = *(const float4*)(wcomp_l + ed.w);
        const float4* xp = (const float4*)(xproj + ed.x * 4 + ci * 8);
        float4 x01 = xp[0];   // b0j0 b0j1 b1j0 b1j1
        float4 x23 = xp[1];   // b2j0 b2j1 b3j0 b3j1

        v2f z = ps + pd + ta + tb;
        z.x = fmaxf(z.x, 0.f);
        z.y = fmaxf(z.y, 0.f);
        float d = fmaf(z.x, bw.x, z.y * bw.y);
        d += __shfl_xor(d, 1);
        d += __shfl_xor(d, 2);
        d += __shfl_xor(d, 4);
        d += __shfl_xor(d, 8);
        float a = __builtin_amdgcn_rcpf(1.f + __expf(-(d + bb)));
        a = valid ? a : 0.f;

        v2f b0 = {x01.x, x01.y};
        v2f b1 = {x01.z, x01.w};
        v2f b2 = {x23.x, x23.y};
        v2f b3 = {x23.z, x23.w};
        v2f m = c.x * b0 + c.y * b1 + c.z * b2 + c.w * b3;
        acc += a * m;
    }
    // reduce the 4 edge-slots: xor 16, xor 32
    acc.x += __shfl_xor(acc.x, 16);
    acc.y += __shfl_xor(acc.y, 16);
    acc.x += __shfl_xor(acc.x, 32);
    acc.y += __shfl_xor(acc.y, 32);
    if (lane < 16) {
        v2f sp = *(const v2f*)(selfp + n * 32 + c2);
        v2f hv;
        hv.x = fmaxf(acc.x + sp.x, 0.f);
        hv.y = fmaxf(acc.y + sp.y, 0.f);
        *(v2f*)(h_next + n * 32 + c2) = hv;
    }
}

// ==================== per-graph mean (8 slices) + head/tail (y=8) ==========
__global__ __launch_bounds__(256) void mean_ht_k(
    const float* __restrict__ h, const int* __restrict__ head_ids,
    const int* __restrict__ tail_ids, float* __restrict__ g_acc,
    float* __restrict__ head_buf, float* __restrict__ tail_buf, int l)
{
    int g  = blockIdx.x;
    int sl = blockIdx.y;
    int i  = threadIdx.x & 31;
    if (sl == 8) {
        if (threadIdx.x < 32)
            head_buf[g*96 + l*32 + i] = h[head_ids[g]*32 + i];
        else if (threadIdx.x < 64)
            tail_buf[g*96 + l*32 + i] = h[tail_ids[g]*32 + i];
        return;
    }
    int sub = threadIdx.x >> 5;
    float acc = 0.f;
    for (int k = sub; k < 125; k += 8)
        acc += h[(g*NPER + sl*125 + k)*32 + i];
    __shared__ float red[8][32];
    red[sub][i] = acc;
    __syncthreads();
    if (threadIdx.x < 32) {
        float s2 = 0.f;
        #pragma unroll
        for (int k = 0; k < 8; k++) s2 += red[k][threadIdx.x];
        atomicAdd(&g_acc[g*96 + l*32 + threadIdx.x], s2 * (1.0f/NPER));
    }
}

// ==================== final readout ====================
__global__ __launch_bounds__(64) void readout_k(
    const float* __restrict__ g_acc, const float* __restrict__ head_buf,
    const float* __restrict__ tail_buf, const float* __restrict__ rel_tab,
    const int* __restrict__ rel_labels, const float* __restrict__ fc_w,
    const float* __restrict__ fc_b, float* __restrict__ out)
{
    int g = blockIdx.x;
    int t = threadIdx.x;
    float s = 0.f;
    for (int idx = t; idx < 320; idx += 64) {
        float v;
        if (idx < 96)       v = g_acc[g*96 + idx];
        else if (idx < 192) v = head_buf[g*96 + idx - 96];
        else if (idx < 288) v = tail_buf[g*96 + idx - 192];
        else                v = rel_tab[rel_labels[g]*32 + (idx - 288)];
        s += v * fc_w[idx];
    }
    s += __shfl_xor(s, 1, 64);
    s += __shfl_xor(s, 2, 64);
    s += __shfl_xor(s, 4, 64);
    s += __shfl_xor(s, 8, 64);
    s += __shfl_xor(s, 16, 64);
    s += __shfl_xor(s, 32, 64);
    if (t == 0) out[g] = s + fc_b[0];
}

extern "C" void kernel_launch(void* const* d_in, const int* in_sizes, int n_in,
                              void* d_out, int out_size, void* d_ws, size_t ws_size,
                              hipStream_t stream) {
    const float* feat        = (const float*)d_in[0];
    const float* basis       = (const float*)d_in[1];   // [3,4,32,32]
    const float* w_comp      = (const float*)d_in[2];   // [3,200,4]
    const float* self_loop_w = (const float*)d_in[3];   // [3,32,32]
    const float* A_w         = (const float*)d_in[4];   // [3,128,32]
    const float* A_b         = (const float*)d_in[5];   // [3,32]
    const float* B_w         = (const float*)d_in[6];   // [3,32,1]
    const float* B_b         = (const float*)d_in[7];   // [3,1]
    const float* attn_tab    = (const float*)d_in[8];   // [200,32]
    const float* rel_tab     = (const float*)d_in[9];   // [200,32]
    const float* fc_w        = (const float*)d_in[10];  // [320,1]
    const float* fc_b        = (const float*)d_in[11];  // [1]
    const int* src        = (const int*)d_in[12];
    const int* dst        = (const int*)d_in[13];
    const int* etype      = (const int*)d_in[14];
    const int* elabel     = (const int*)d_in[15];
    const int* head_ids   = (const int*)d_in[17];
    const int* tail_ids   = (const int*)d_in[18];
    const int* rel_labels = (const int*)d_in[19];

    float* ws = (float*)d_ws;
    size_t off = 0;
    float* h0    = ws + off; off += (size_t)NNODES * 32;
    float* h1    = ws + off; off += (size_t)NNODES * 32;
    float* xproj = ws + off; off += (size_t)NNODES * 128;
    float* psrc  = ws + off; off += (size_t)NNODES * 32;
    float* pdst  = ws + off; off += (size_t)NNODES * 32;
    float* selfp = ws + off; off += (size_t)NNODES * 32;
    float* t1    = ws + off; off += 200 * 32;
    float* t2    = ws + off; off += 200 * 32;
    float* g_acc    = ws + off; off += NGRAPH * 96;
    float* head_buf = ws + off; off += NGRAPH * 96;
    float* tail_buf = ws + off; off += NGRAPH * 96;
    int* count  = (int*)(ws + off); off += NNODES;
    int* offs   = (int*)(ws + off); off += NNODES;
    int* cursor = (int*)(ws + off); off += NNODES;
    off = (off + 3) & ~(size_t)3;               // 16 B align
    int4* sorted = (int4*)(ws + off); off += (size_t)NEDGES * 4;

    // ---- one-time per call: CSR by dst + zero mean accumulator ----
    zero2_k<<<(NNODES + 255)/256, 256, 0, stream>>>(count, g_acc);
    hist_k<<<(NEDGES + 255)/256, 256, 0, stream>>>(dst, count);
    scan_k<<<NGRAPH, 1024, 0, stream>>>(count, offs, cursor);
    scatter_k<<<(NEDGES + 255)/256, 256, 0, stream>>>(src, dst, etype, elabel,
                                                      cursor, sorted);

    const float* hcur = feat;
    float* hbufs[2] = { h0, h1 };
    for (int l = 0; l < 3; l++) {
        dim3 ngrid((NNODES + 255)/256, 7);
        node_k<<<ngrid, 256, 0, stream>>>(
            hcur, basis + (size_t)l*4096, self_loop_w + (size_t)l*1024,
            A_w + (size_t)l*4096, A_b + (size_t)l*32, attn_tab,
            xproj, psrc, pdst, selfp, t1, t2);
        float* hn = hbufs[l & 1];
        edge_csr_k<<<NNODES/4, 256, 0, stream>>>(
            sorted, offs, psrc, pdst, t1, t2, xproj, selfp,
            w_comp + (size_t)l*800, B_w + (size_t)l*32, B_b + l, hn);
        dim3 mgrid(NGRAPH, 9);
        mean_ht_k<<<mgrid, 256, 0, stream>>>(
            hn, head_ids, tail_ids, g_acc, head_buf, tail_buf, l);
        hcur = hn;
    }
    readout_k<<<NGRAPH, 64, 0, stream>>>(
        g_acc, head_buf, tail_buf, rel_tab, rel_labels, fc_w, fc_b, (float*)d_out);
}